// Round 1
// baseline (5796.949 us; speedup 1.0000x reference)
//
#include <hip/hip_runtime.h>

#define T_STEPS 256
#define BATCH   25
#define VOCAB   32000
#define HID     1024

typedef _Float16 half8  __attribute__((ext_vector_type(8)));
typedef float    floatx4  __attribute__((ext_vector_type(4)));
typedef float    floatx16 __attribute__((ext_vector_type(16)));

// ---------------------------------------------------------------------------
// ws layout (bytes):
//   P   : 6400*1024*4      = 26,214,400
//   Bt  : 1024*32000*2     = 65,536,000   (W_xh transposed, f16, [n][k])
//   hA  : 32*1024*2        = 65,536
//   hB  : 32*1024*2        = 65,536
//   cnt : 4 (barrier counter)
// total ~ 87.7 MB
// ---------------------------------------------------------------------------
#define OFF_BT  (26214400)
#define OFF_HA  (26214400 + 65536000)
#define OFF_HB  (26214400 + 65536000 + 65536)
#define OFF_CNT (26214400 + 65536000 + 131072)

// ===========================================================================
// K1: transpose-convert W_xh (32000 x 1024 fp32) -> Bt (1024 x 32000 f16)
// Also zero-inits the grid-barrier counter (runs first on the stream).
// ===========================================================================
__global__ __launch_bounds__(256) void k_transpose(const float* __restrict__ W,
                                                   _Float16* __restrict__ Bt,
                                                   int* __restrict__ cnt) {
    if (blockIdx.x == 0 && blockIdx.y == 0 && threadIdx.x == 0) *cnt = 0;
    __shared__ _Float16 tile[64][72];   // +8 pad to break bank conflicts
    const int k0 = blockIdx.x * 64;
    const int n0 = blockIdx.y * 64;
    const int t  = threadIdx.x;
    #pragma unroll
    for (int i = 0; i < 4; ++i) {
        int s  = t + i * 256;           // 0..1023
        int r  = s >> 4;                // k row in tile
        int c4 = (s & 15) * 4;          // n col in tile
        const float4 v = *(const float4*)(W + (size_t)(k0 + r) * HID + n0 + c4);
        tile[r][c4 + 0] = (_Float16)v.x;
        tile[r][c4 + 1] = (_Float16)v.y;
        tile[r][c4 + 2] = (_Float16)v.z;
        tile[r][c4 + 3] = (_Float16)v.w;
    }
    __syncthreads();
    #pragma unroll
    for (int i = 0; i < 2; ++i) {
        int s  = t + i * 256;           // 0..511
        int nr = s >> 3;                // n row in tile
        int k8 = (s & 7) * 8;
        half8 h;
        #pragma unroll
        for (int j = 0; j < 8; ++j) h[j] = tile[k8 + j][nr];
        *(half8*)(Bt + (size_t)(n0 + nr) * VOCAB + k0 + k8) = h;
    }
}

// ===========================================================================
// K2: P = X @ W_xh  via f16 MFMA.  M=6400 (=T*B), K=32000, N=1024.
// 128x128 tile, BK=32, fragment-order LDS (conflict-free b128 reads).
// XCD-grouped swizzle: the 8 N-tiles of one M-strip land on ONE XCD so the
// X strip is fetched once per XCD-group through L2.
// ===========================================================================
__global__ __launch_bounds__(256) void k_gemm(const float* __restrict__ X,
                                              const _Float16* __restrict__ Bt,
                                              float* __restrict__ P) {
    const int bid = blockIdx.x;
    const int c   = bid & 7;
    const int j   = bid >> 3;
    const int mt  = (j >> 3) * 8 + c;   // M-tile
    const int nt  = j & 7;              // N-tile
    if (mt >= 50) return;
    const int m0 = mt * 128, n0 = nt * 128;

    // fragment-order staging: tile ti (16 rows) -> 64 lanes x 8 halves
    __shared__ _Float16 sA[4096];   // 8 KB
    __shared__ _Float16 sB[4096];   // 8 KB

    const int tid  = threadIdx.x;
    const int lane = tid & 63;
    const int wv   = tid >> 6;       // wave 0..3
    const int wm   = wv >> 1;        // 0..1 (m half)
    const int wn   = wv & 1;         // 0..1 (n half)

    floatx4 acc[4][4];
    #pragma unroll
    for (int i = 0; i < 4; ++i)
        #pragma unroll
        for (int jj = 0; jj < 4; ++jj) acc[i][jj] = 0.0f;

    for (int kc = 0; kc < VOCAB / 32; ++kc) {
        const int k0 = kc * 32;
        __syncthreads();
        #pragma unroll
        for (int r = 0; r < 2; ++r) {
            int s  = tid + r * 256;          // 0..511
            int m  = s >> 2;                 // row in tile (0..127)
            int ko = s & 3;                  // k-octet (0..3)
            // A: fp32 load + convert
            const float4* gp = (const float4*)(X + (size_t)(m0 + m) * VOCAB + k0 + ko * 8);
            float4 v0 = gp[0], v1 = gp[1];
            half8 ha;
            ha[0] = (_Float16)v0.x; ha[1] = (_Float16)v0.y;
            ha[2] = (_Float16)v0.z; ha[3] = (_Float16)v0.w;
            ha[4] = (_Float16)v1.x; ha[5] = (_Float16)v1.y;
            ha[6] = (_Float16)v1.z; ha[7] = (_Float16)v1.w;
            int ti = m >> 4;
            int li = (ko << 4) | (m & 15);   // fragment lane
            *(half8*)&sA[ti * 512 + li * 8] = ha;
            // B: already f16, direct 16B copy
            half8 hb = *(const half8*)(Bt + (size_t)(n0 + m) * VOCAB + k0 + ko * 8);
            *(half8*)&sB[ti * 512 + li * 8] = hb;
        }
        __syncthreads();
        half8 af[4], bf[4];
        #pragma unroll
        for (int i = 0; i < 4; ++i) af[i] = *(const half8*)&sA[(wm * 4 + i) * 512 + lane * 8];
        #pragma unroll
        for (int i = 0; i < 4; ++i) bf[i] = *(const half8*)&sB[(wn * 4 + i) * 512 + lane * 8];
        #pragma unroll
        for (int i = 0; i < 4; ++i)
            #pragma unroll
            for (int jj = 0; jj < 4; ++jj)
                acc[i][jj] = __builtin_amdgcn_mfma_f32_16x16x32_f16(af[i], bf[jj], acc[i][jj], 0, 0, 0);
    }

    // epilogue: C layout col=lane&15, row=(lane>>4)*4+reg
    const int quad = lane >> 4, col = lane & 15;
    #pragma unroll
    for (int i = 0; i < 4; ++i) {
        int mg = m0 + wm * 64 + i * 16 + quad * 4;
        #pragma unroll
        for (int jj = 0; jj < 4; ++jj) {
            int ng = n0 + wn * 64 + jj * 16 + col;
            #pragma unroll
            for (int r = 0; r < 4; ++r)
                P[(size_t)(mg + r) * HID + ng] = acc[i][jj][r];
        }
    }
}

// ===========================================================================
// device-scope grid barrier (32 co-resident blocks; counter monotonic)
// ===========================================================================
__device__ __forceinline__ void gbar(int* cnt, int target) {
    __syncthreads();
    if (threadIdx.x == 0) {
        __threadfence();                 // release: drain to coherent point
        atomicAdd(cnt, 1);               // device-scope by default
        while (__hip_atomic_load(cnt, __ATOMIC_ACQUIRE, __HIP_MEMORY_SCOPE_AGENT) < target) {
            __builtin_amdgcn_s_sleep(1);
        }
    }
    __syncthreads();
    __threadfence();                     // acquire: invalidate stale caches
}

// ===========================================================================
// K3: persistent recurrence + head.  32 WGs x 1 wave.
// WG w owns hidden columns [w*32, w*32+32).  Its W_hh slice lives in LDS in
// MFMA-B-fragment order (64 KB, loaded once).  Per step: one barrier, then
// 64 chained mfma_32x32x16_f16 (2 accumulators), tanh epilogue, h stored f16
// in double-buffered global arrays.
// ===========================================================================
__global__ __launch_bounds__(64) void k_rec(const float* __restrict__ P,
                                            const float* __restrict__ Whh,
                                            const float* __restrict__ bh,
                                            const float* __restrict__ fcw,
                                            const float* __restrict__ fcb,
                                            _Float16* __restrict__ hA,
                                            _Float16* __restrict__ hB,
                                            float* __restrict__ out,
                                            int* __restrict__ cnt) {
    const int wg   = blockIdx.x;     // 0..31
    const int lane = threadIdx.x;    // 0..63
    const int n0   = wg * 32;

    // B-fragment order: smem[kk*512 + lane*8 + j] = Whh[kk*16 + (lane>>5)*8 + j][n0 + (lane&31)]
    __shared__ _Float16 smem[32768];  // 64 KB

    {
        const int n  = lane & 31;
        const int kh = lane >> 5;
        for (int kk = 0; kk < 64; ++kk) {
            half8 h;
            #pragma unroll
            for (int jj = 0; jj < 8; ++jj) {
                int k = kk * 16 + kh * 8 + jj;
                h[jj] = (_Float16)Whh[(size_t)k * HID + n0 + n];
            }
            *(half8*)&smem[kk * 512 + lane * 8] = h;
        }
    }

    // zero-init h0 (all 2048 threads, 16 halves each -> full 32x1024)
    {
        int gid = wg * 64 + lane;
        float4 z = {0.f, 0.f, 0.f, 0.f};
        *(float4*)(hA + gid * 16)     = z;
        *(float4*)(hA + gid * 16 + 8) = z;
    }

    int barNum = 0;
    const _Float16* R  = hA;
    _Float16*       Wb = hB;
    const int m  = lane & 31;   // batch row for A-frag / output col for C
    const int kh = lane >> 5;

    for (int t = 0; t < T_STEPS; ++t) {
        gbar(cnt, (++barNum) * 32);   // makes prev step's h (and h0 init) visible

        floatx16 c0 = 0.0f, c1 = 0.0f;
        #pragma unroll 4
        for (int kk = 0; kk < 64; kk += 2) {
            half8 a0 = *(const half8*)(R + (size_t)m * HID + kk * 16 + kh * 8);
            half8 b0 = *(const half8*)&smem[kk * 512 + lane * 8];
            half8 a1 = *(const half8*)(R + (size_t)m * HID + (kk + 1) * 16 + kh * 8);
            half8 b1 = *(const half8*)&smem[(kk + 1) * 512 + lane * 8];
            c0 = __builtin_amdgcn_mfma_f32_32x32x16_f16(a0, b0, c0, 0, 0, 0);
            c1 = __builtin_amdgcn_mfma_f32_32x32x16_f16(a1, b1, c1, 0, 0, 0);
        }

        const float* Pt = P + (size_t)t * BATCH * HID;
        #pragma unroll
        for (int r = 0; r < 16; ++r) {
            int row = (r & 3) + 8 * (r >> 2) + 4 * kh;   // C layout, 32x32 shape
            if (row < BATCH) {
                int colg  = n0 + m;
                float pre = c0[r] + c1[r] + Pt[row * HID + colg] + bh[colg];
                Wb[(size_t)row * HID + colg] = (_Float16)tanhf(pre);
            }
        }
        // swap double buffers
        _Float16* tmp = Wb; Wb = (_Float16*)R; R = tmp;
    }

    gbar(cnt, (++barNum) * 32);   // final h visible to WG 0

    if (wg == 0) {
        float l0 = 0.f, l1 = 0.f;
        for (int col = lane; col < HID; col += 64) {
            float s = 0.f;
            for (int b = 0; b < BATCH; ++b) s += (float)R[(size_t)b * HID + col];
            float pooled = s * (1.0f / BATCH);
            l0 += pooled * fcw[col * 2 + 0];
            l1 += pooled * fcw[col * 2 + 1];
        }
        #pragma unroll
        for (int off = 32; off > 0; off >>= 1) {
            l0 += __shfl_down(l0, off);
            l1 += __shfl_down(l1, off);
        }
        if (lane == 0) {
            l0 += fcb[0]; l1 += fcb[1];
            float mx = fmaxf(l0, l1);
            float e0 = __expf(l0 - mx), e1 = __expf(l1 - mx);
            float inv = 1.0f / (e0 + e1);
            out[0] = e0 * inv;
            out[1] = e1 * inv;
        }
    }
}

// ===========================================================================
extern "C" void kernel_launch(void* const* d_in, const int* in_sizes, int n_in,
                              void* d_out, int out_size, void* d_ws, size_t ws_size,
                              hipStream_t stream) {
    const float* X   = (const float*)d_in[0];
    const float* Wxh = (const float*)d_in[1];
    const float* Whh = (const float*)d_in[2];
    const float* bh  = (const float*)d_in[3];
    const float* fcw = (const float*)d_in[4];
    const float* fcb = (const float*)d_in[5];

    char* ws = (char*)d_ws;
    float*    P   = (float*)ws;
    _Float16* Bt  = (_Float16*)(ws + OFF_BT);
    _Float16* hA  = (_Float16*)(ws + OFF_HA);
    _Float16* hB  = (_Float16*)(ws + OFF_HB);
    int*      cnt = (int*)(ws + OFF_CNT);

    hipLaunchKernelGGL(k_transpose, dim3(500, 16), dim3(256), 0, stream, Wxh, Bt, cnt);
    hipLaunchKernelGGL(k_gemm, dim3(448), dim3(256), 0, stream, X, Bt, P);
    hipLaunchKernelGGL(k_rec, dim3(32), dim3(64), 0, stream,
                       P, Whh, bh, fcw, fcb, hA, hB, (float*)d_out, cnt);
}